// Round 11
// baseline (64.323 us; speedup 1.0000x reference)
//
#include <hip/hip_runtime.h>
#include <math.h>

// Mamba selective scan:
//   u, delta, z : (2, 2048, 1024) f32 ; A : (2048, 16) f32
//   B, C : (2, 16, 1024) f32 ; D, delta_bias : (2048,) f32 ; softplus flag
// Output y : (2, 2048, 1024) f32
//
// v17 = v16 (49.4 us: RPB=4, B/C LDS tiles, proven combine) with du_s
//       ELIMINATED -- all per-thread data in registers:
//   - each thread owns chunk cg's 16 contiguous elements: dt[16], uu[16]
//     loaded directly from global (4+4 float4, dense per wave). No
//     phase0 LDS transpose, no barrier before pass 1 (except tile 0).
//   - y_core kept in registers (in-place over uu after shfl_xor gives
//     both halves the full sum); epilogue stores 32 B/lane, dense.
//   - freed 33 KB LDS -> 4-buffer pass-2 double-buffer (tbB[2]+tbC[2]):
//     barriers 25 -> 16 (one per tile epoch).
//   - tile t loops FULLY unrolled (static dt[i]/uu[i] indexing, rule #20).
//   - NO register cap (r2/r4). Tripwire: WRITE_SIZE == 16384 KB.
constexpr int Bsz = 2, Dm = 2048, L = 1024, N = 16;
constexpr int CL = 16;          // chunk length (steps per lane)
constexpr int WPR = 2;          // waves per row
constexpr int RPB = 4;          // rows per block
constexpr int TPB = RPB * WPR * 64;  // 512
constexpr int TI = 2;           // steps per LDS tile
constexpr int NT = CL / TI;     // 8 tiles per pass
constexpr float LOG2E = 1.4426950408889634f;
constexpr float RLOG2E = 0.6931471805599453f;   // ln 2

#define EXP2(x) __builtin_amdgcn_exp2f(x)
// swizzled float4 index within a tile: il in [0,TI), cg in [0,64), k in [0,4)
#define TOFF(il, cg, k) ((il) * 256 + (cg) * 4 + ((k) ^ (((cg) >> 1) & 3)))

// ---------------------------------------------------------------------------
// Transform B,C into scan layout (chunk length 16), k-contiguous:
//   Bs[b*4096 + i*256 + cg*4 + k] = float4 { B[b][4k+q][cg*16+i] } q=0..3
// ---------------------------------------------------------------------------
__global__ __launch_bounds__(256) void transform_bc_kernel(
    const float* __restrict__ B_g, const float* __restrict__ C_g,
    float4* __restrict__ Bs, float4* __restrict__ Cs)
{
    const int o = threadIdx.x + 256 * blockIdx.x;   // 4096 float4 per (b, src)
    const int b = blockIdx.y;
    const float* __restrict__ src = blockIdx.z ? C_g : B_g;
    float4* __restrict__ dst = blockIdx.z ? Cs : Bs;
    const int k = o & 3, cg = (o >> 2) & 63, i = o >> 8;
    const int l = cg * CL + i;
    float4 v;
    v.x = src[(size_t)(b * N + 4 * k + 0) * L + l];
    v.y = src[(size_t)(b * N + 4 * k + 1) * L + l];
    v.z = src[(size_t)(b * N + 4 * k + 2) * L + l];
    v.w = src[(size_t)(b * N + 4 * k + 3) * L + l];
    dst[(size_t)b * 4096 + o] = v;
}

// ---------------------------------------------------------------------------
// Scan kernel. 8 waves/block = 4 rows x 2 waves. Wave handles 32 chunks of
// 16 steps. lane = h*32 + c: h = n-half, c = chunk-in-wave. cg = W*32+c.
// B/C tiles shared by all 4 rows via LDS; everything else in registers.
// ---------------------------------------------------------------------------
template<bool XF>
__global__ __launch_bounds__(TPB) void mamba_scan17_kernel(
    const float* __restrict__ u_g, const float* __restrict__ delta_g,
    const float* __restrict__ A_g,
    const float* __restrict__ B_g, const float* __restrict__ C_g,
    const float4* __restrict__ Bs, const float4* __restrict__ Cs,
    const float* __restrict__ D_g, const float* __restrict__ z_g,
    const float* __restrict__ bias_g, const int* __restrict__ sp_g,
    float* __restrict__ y_g)
{
    __shared__ float4 tbB[2][TI * 256];   // 16 KB: B tile double-buffer
    __shared__ float4 tbC[2][TI * 256];   // 16 KB: C tile double-buffer
    __shared__ float xw_s[RPB][16];       // per-row wave0 totals

    const int tid = threadIdx.x;
    const int wid = tid >> 6;                  // wave id 0..7
    const int lane = tid & 63;
    const int W = wid & 1;                     // wave-in-row
    const int r = wid >> 1;                    // local row 0..3
    const int h = lane >> 5;                   // n-half
    const int c = lane & 31;                   // chunk-in-wave
    const int cg = W * 32 + c;                 // global chunk 0..63
    const int row = blockIdx.x * RPB + r;
    const int b = row >> 11;                   // row / Dm (blocks never straddle)
    const int d = row & (Dm - 1);
    const int stg = TOFF(tid >> 8, (tid >> 2) & 63, tid & 3);
    const size_t Bb = (size_t)b * 4096;        // workspace base (float4 units)
    const int k0 = 2 * h;                      // my first n-quad

    float4 sB, sC;
    if (XF) sB = Bs[Bb + tid];                 // tile 0 of B, issued early

    // ---- Phase 0: per-thread chunk-contiguous delta/u -> REGISTERS ----
    const size_t gch = (size_t)row * L + cg * CL;   // my 16 elements
    float dt[CL], uu[CL];
    {
        const float bias = bias_g[d];
        const int sp = sp_g[0];
#pragma unroll
        for (int p = 0; p < 4; ++p) {
            const float4 d4 = *reinterpret_cast<const float4*>(&delta_g[gch + 4 * p]);
            const float4 u4 = *reinterpret_cast<const float4*>(&u_g[gch + 4 * p]);
#pragma unroll
            for (int k = 0; k < 4; ++k) {
                const float t = (&d4.x)[k] + bias;
                // softplus: max(t,0) + ln(1 + 2^(-|t|*log2e))
                const float e = EXP2(-fabsf(t) * LOG2E);
                dt[4 * p + k] = sp ? (fmaxf(t, 0.f) +
                                      __builtin_amdgcn_logf(1.f + e) * RLOG2E)
                                   : t;
                uu[4 * p + k] = (&u4.x)[k];
            }
        }
    }
    float A2[8];
#pragma unroll
    for (int g = 0; g < 2; ++g) {
        const float4 a4 = *reinterpret_cast<const float4*>(&A_g[d * N + h * 8 + g * 4]);
        A2[g * 4 + 0] = a4.x * LOG2E; A2[g * 4 + 1] = a4.y * LOG2E;
        A2[g * 4 + 2] = a4.z * LOG2E; A2[g * 4 + 3] = a4.w * LOG2E;
    }
    if (XF) tbB[0][stg] = sB;                  // stage tile 0 (B) for pass 1
    __syncthreads();

    // ---- Pass 1: chunk-local zero-init scan; B via LDS tiles (dbuf) ----
    float x[8];
#pragma unroll
    for (int n = 0; n < 8; ++n) x[n] = 0.f;
    float ssum = 0.f;

    if (XF) {
#pragma unroll
        for (int t = 0; t < NT; ++t) {
            if (t + 1 < NT) sB = Bs[Bb + (t + 1) * 512 + tid];  // prefetch
#pragma unroll
            for (int il = 0; il < TI; ++il) {
                const int i = t * TI + il;     // compile-time (full unroll)
                const float dtp = dt[i];
                const float dtu = dtp * uu[i];
                ssum += dtp;
                const float4 B0 = tbB[t & 1][TOFF(il, cg, k0)];
                const float4 B1 = tbB[t & 1][TOFF(il, cg, k0 + 1)];
                const float bv[8] = {B0.x, B0.y, B0.z, B0.w, B1.x, B1.y, B1.z, B1.w};
#pragma unroll
                for (int n = 0; n < 8; ++n) {
                    const float a = EXP2(dtp * A2[n]);
                    x[n] = fmaf(a, x[n], dtu * bv[n]);
                }
            }
            if (t + 1 < NT) tbB[(t + 1) & 1][stg] = sB;
            __syncthreads();                   // end tile epoch
        }
    } else {
#pragma unroll
        for (int i = 0; i < CL; ++i) {
            const float dtp = dt[i];
            const float dtu = dtp * uu[i];
            ssum += dtp;
            const int l = cg * CL + i;
            float4 B0, B1;
#pragma unroll
            for (int q = 0; q < 4; ++q) {
                (&B0.x)[q] = B_g[(size_t)(b * N + 4 * k0 + q) * L + l];
                (&B1.x)[q] = B_g[(size_t)(b * N + 4 * k0 + 4 + q) * L + l];
            }
            const float bv[8] = {B0.x, B0.y, B0.z, B0.w, B1.x, B1.y, B1.z, B1.w};
#pragma unroll
            for (int n = 0; n < 8; ++n) {
                const float a = EXP2(dtp * A2[n]);
                x[n] = fmaf(a, x[n], dtu * bv[n]);
            }
        }
    }

    // issue pass-2 tile 0 loads early (latency hides under combine)
    if (XF) { sB = Bs[Bb + tid]; sC = Cs[Bb + tid]; }

    // ---- Combine level 1: 32-lane segmented inclusive scan of (P, x) ----
    float P[8];
#pragma unroll
    for (int n = 0; n < 8; ++n) P[n] = EXP2(A2[n] * ssum);
#pragma unroll
    for (int s = 1; s < 32; s <<= 1) {
        const bool ok = (c >= s);
#pragma unroll
        for (int n = 0; n < 8; ++n) {
            const float xp = __shfl_up(x[n], s, 32);
            const float Pp = __shfl_up(P[n], s, 32);
            if (ok) {
                x[n] = fmaf(P[n], xp, x[n]);
                P[n] = P[n] * Pp;
            }
        }
    }

    // ---- Combine level 2 publish + stage pass-2 tile 0; ONE barrier ----
    if (W == 0 && c == 31) {
#pragma unroll
        for (int n = 0; n < 8; ++n) xw_s[r][h * 8 + n] = x[n];
    }
    if (XF) { tbB[0][stg] = sB; tbC[0][stg] = sC; }
    __syncthreads();

    // exclusive shift within segment + wave1 prepends wave0's total
    float xt[8];
#pragma unroll
    for (int n = 0; n < 8; ++n) xt[n] = xw_s[r][h * 8 + n];
#pragma unroll
    for (int n = 0; n < 8; ++n) {
        const float xi = __shfl_up(x[n], 1, 32);
        const float Pi = __shfl_up(P[n], 1, 32);
        const float xe = (c == 0) ? 0.f : xi;
        const float Pe = (c == 0) ? 1.f : Pi;
        x[n] = W ? fmaf(Pe, xt[n], xe) : xe;
    }

    // ---- Pass 2: rescan with init states; y -> uu[] in place ----
    const float Dd = D_g[d];
    if (XF) {
#pragma unroll
        for (int t = 0; t < NT; ++t) {
            if (t + 1 < NT) {
                sB = Bs[Bb + (t + 1) * 512 + tid];   // prefetch next tile
                sC = Cs[Bb + (t + 1) * 512 + tid];
            }
#pragma unroll
            for (int il = 0; il < TI; ++il) {
                const int i = t * TI + il;
                const float dtp = dt[i];
                const float dtu = dtp * uu[i];
                const float4 B0 = tbB[t & 1][TOFF(il, cg, k0)];
                const float4 B1 = tbB[t & 1][TOFF(il, cg, k0 + 1)];
                const float4 C0 = tbC[t & 1][TOFF(il, cg, k0)];
                const float4 C1 = tbC[t & 1][TOFF(il, cg, k0 + 1)];
                const float bv[8] = {B0.x, B0.y, B0.z, B0.w, B1.x, B1.y, B1.z, B1.w};
                const float cv[8] = {C0.x, C0.y, C0.z, C0.w, C1.x, C1.y, C1.z, C1.w};
                float acc = 0.f;
#pragma unroll
                for (int n = 0; n < 8; ++n) {
                    const float a = EXP2(dtp * A2[n]);
                    x[n] = fmaf(a, x[n], dtu * bv[n]);
                    acc = fmaf(x[n], cv[n], acc);
                }
                acc += __shfl_xor(acc, 32, 64);    // both halves get full sum
                uu[i] = fmaf(uu[i], Dd, acc);      // y_core in place
            }
            if (t + 1 < NT) {
                tbB[(t + 1) & 1][stg] = sB;        // write other buffer
                tbC[(t + 1) & 1][stg] = sC;
                __syncthreads();                   // one barrier per tile
            }
        }
    } else {
#pragma unroll
        for (int i = 0; i < CL; ++i) {
            const float dtp = dt[i];
            const float dtu = dtp * uu[i];
            const int l = cg * CL + i;
            float4 B0, B1, C0, C1;
#pragma unroll
            for (int q = 0; q < 4; ++q) {
                (&B0.x)[q] = B_g[(size_t)(b * N + 4 * k0 + q) * L + l];
                (&B1.x)[q] = B_g[(size_t)(b * N + 4 * k0 + 4 + q) * L + l];
                (&C0.x)[q] = C_g[(size_t)(b * N + 4 * k0 + q) * L + l];
                (&C1.x)[q] = C_g[(size_t)(b * N + 4 * k0 + 4 + q) * L + l];
            }
            const float bv[8] = {B0.x, B0.y, B0.z, B0.w, B1.x, B1.y, B1.z, B1.w};
            const float cv[8] = {C0.x, C0.y, C0.z, C0.w, C1.x, C1.y, C1.z, C1.w};
            float acc = 0.f;
#pragma unroll
            for (int n = 0; n < 8; ++n) {
                const float a = EXP2(dtp * A2[n]);
                x[n] = fmaf(a, x[n], dtu * bv[n]);
                acc = fmaf(x[n], cv[n], acc);
            }
            acc += __shfl_xor(acc, 32, 64);
            uu[i] = fmaf(uu[i], Dd, acc);
        }
    }

    // ---- Epilogue: per-lane z read (32B), silu gate, y store (32B) ----
    // lane (h,c) handles elements [cg*16 + h*8, +8); wave coverage dense.
    {
        const size_t gz = gch + h * 8;
        const float4 z0 = *reinterpret_cast<const float4*>(&z_g[gz]);
        const float4 z1 = *reinterpret_cast<const float4*>(&z_g[gz + 4]);
        float out[8];
#pragma unroll
        for (int j = 0; j < 8; ++j) {
            const float zv = (j < 4) ? (&z0.x)[j] : (&z1.x)[j - 4];
            const float yc = h ? uu[8 + j] : uu[j];   // static indices
            const float e = EXP2(-zv * LOG2E);
            const float sig = __builtin_amdgcn_rcpf(1.f + e);
            out[j] = yc * (zv * sig);
        }
        *reinterpret_cast<float4*>(&y_g[gz]) =
            make_float4(out[0], out[1], out[2], out[3]);
        *reinterpret_cast<float4*>(&y_g[gz + 4]) =
            make_float4(out[4], out[5], out[6], out[7]);
    }
}

extern "C" void kernel_launch(void* const* d_in, const int* in_sizes, int n_in,
                              void* d_out, int out_size, void* d_ws, size_t ws_size,
                              hipStream_t stream) {
    const float* u     = (const float*)d_in[0];
    const float* delta = (const float*)d_in[1];
    const float* A     = (const float*)d_in[2];
    const float* B     = (const float*)d_in[3];
    const float* C     = (const float*)d_in[4];
    const float* D     = (const float*)d_in[5];
    const float* z     = (const float*)d_in[6];
    const float* bias  = (const float*)d_in[7];
    const int*   sp    = (const int*)d_in[8];
    float* y = (float*)d_out;

    const size_t bc_bytes = (size_t)Bsz * 4096 * sizeof(float4);  // 128 KB each
    const bool xf = ws_size >= 2 * bc_bytes;
    float4* Bs = (float4*)d_ws;
    float4* Cs = (float4*)((char*)d_ws + bc_bytes);

    if (xf) {
        transform_bc_kernel<<<dim3(16, Bsz, 2), 256, 0, stream>>>(B, C, Bs, Cs);
        mamba_scan17_kernel<true><<<dim3((Bsz * Dm) / RPB), TPB, 0, stream>>>(
            u, delta, A, B, C, Bs, Cs, D, z, bias, sp, y);
    } else {
        mamba_scan17_kernel<false><<<dim3((Bsz * Dm) / RPB), TPB, 0, stream>>>(
            u, delta, A, B, C, Bs, Cs, D, z, bias, sp, y);
    }
}

// Round 12
// 49.548 us; speedup vs baseline: 1.2982x; 1.2982x over previous
//
#include <hip/hip_runtime.h>
#include <math.h>

// Mamba selective scan:
//   u, delta, z : (2, 2048, 1024) f32 ; A : (2048, 16) f32
//   B, C : (2, 16, 1024) f32 ; D, delta_bias : (2048,) f32 ; softplus flag
// Output y : (2, 2048, 1024) f32
//
// v18 = v16 (49.4 us: RPB=4, B/C LDS tiles, proven combine) + LDS-pipe cuts:
//   - tile layout [il][j][cg] float2, stride 65: ALL tile accesses are
//     ds_read_b64 / ds_write_b64 at 2-way bank aliasing (free) -- the b128
//     4-way conflict (3.4M cycles) is inherent (b128 => 8 slots/32 lanes),
//     b64 has 16 slots => 2-way. Transform emits k-major to keep staging
//     global reads coalesced.
//   - y_core in 8 regs (static idx via full unroll + cndmask on h);
//     epilogue stores 32B/lane dense from regs. Removes 32 LDS ops and the
//     final barrier. +8 VGPR only (v17 lesson: keep persistent arrays <=16).
//   - everything else byte-identical to v16 (barrier scheme, combine, du_s).
//   - NO register cap (r2/r4). Tripwires: WRITE_SIZE == 16384 KB,
//     SQ_LDS_BANK_CONFLICT < 1M.
constexpr int Bsz = 2, Dm = 2048, L = 1024, N = 16;
constexpr int CL = 16;          // chunk length (steps per lane)
constexpr int WPR = 2;          // waves per row
constexpr int RPB = 4;          // rows per block
constexpr int TPB = RPB * WPR * 64;  // 512
constexpr int TI = 2;           // steps per LDS tile
constexpr int NT = CL / TI;     // 8 tiles per pass
constexpr int ISTR2 = 65;       // du_s float2 stride per step (64 + 1 pad)
constexpr int LROW2 = CL * ISTR2;    // 1040 float2 per row
constexpr int TS2 = 8 * 65;     // tile: float2 stride per il (8 j-slots x 65)
constexpr float LOG2E = 1.4426950408889634f;
constexpr float RLOG2E = 0.6931471805599453f;   // ln 2

#define EXP2(x) __builtin_amdgcn_exp2f(x)

// ---------------------------------------------------------------------------
// Transform B,C into scan layout (chunk length 16), k-MAJOR:
//   Bs[b*4096 + i*256 + k*64 + cg] = float4 { B[b][4k+q][cg*16+i] } q=0..3
// Staging thread tid of tile t then reads Bs[t*512 + tid] fully coalesced.
// ---------------------------------------------------------------------------
__global__ __launch_bounds__(256) void transform_bc_kernel(
    const float* __restrict__ B_g, const float* __restrict__ C_g,
    float4* __restrict__ Bs, float4* __restrict__ Cs)
{
    const int o = threadIdx.x + 256 * blockIdx.x;   // 4096 float4 per (b, src)
    const int b = blockIdx.y;
    const float* __restrict__ src = blockIdx.z ? C_g : B_g;
    float4* __restrict__ dst = blockIdx.z ? Cs : Bs;
    const int cg = o & 63, k = (o >> 6) & 3, i = o >> 8;
    const int l = cg * CL + i;
    float4 v;
    v.x = src[(size_t)(b * N + 4 * k + 0) * L + l];
    v.y = src[(size_t)(b * N + 4 * k + 1) * L + l];
    v.z = src[(size_t)(b * N + 4 * k + 2) * L + l];
    v.w = src[(size_t)(b * N + 4 * k + 3) * L + l];
    dst[(size_t)b * 4096 + o] = v;
}

// ---------------------------------------------------------------------------
// Scan kernel. 8 waves/block = 4 rows x 2 waves. Wave handles 32 chunks of
// 16 steps. lane = h*32 + c: h = n-half, c = chunk-in-wave. cg = W*32+c.
// B/C tiles shared by all 4 rows via LDS (b64 conflict-free layout).
// ---------------------------------------------------------------------------
template<bool XF>
__global__ __launch_bounds__(TPB) void mamba_scan18_kernel(
    const float* __restrict__ u_g, const float* __restrict__ delta_g,
    const float* __restrict__ A_g,
    const float* __restrict__ B_g, const float* __restrict__ C_g,
    const float4* __restrict__ Bs, const float4* __restrict__ Cs,
    const float* __restrict__ D_g, const float* __restrict__ z_g,
    const float* __restrict__ bias_g, const int* __restrict__ sp_g,
    float* __restrict__ y_g)
{
    __shared__ float2 du_s[RPB * LROW2];  // [r][i*65+cg] = (dtp,u)
    __shared__ float2 tb2[2][TI * TS2];   // 16.6 KB: tile buffers (b64 layout)
    __shared__ float xw_s[RPB][16];       // per-row wave0 totals

    const int tid = threadIdx.x;
    const int wid = tid >> 6;                  // wave id 0..7
    const int lane = tid & 63;
    const int W = wid & 1;                     // wave-in-row
    const int r = wid >> 1;                    // local row 0..3
    const int h = lane >> 5;                   // n-half
    const int c = lane & 31;                   // chunk-in-wave
    const int cg = W * 32 + c;                 // global chunk 0..63
    const int row = blockIdx.x * RPB + r;
    const int b = row >> 11;                   // row / Dm (blocks never straddle)
    const int d = row & (Dm - 1);
    const size_t Bb = (size_t)b * 4096;        // workspace base (float4 units)
    const int lb = r * LROW2;
    const int t128 = tid & 127;                // thread-in-row (2 waves)
    // staging: wave wid owns (il = wid>>2, k = wid&3) for all 64 cg
    const int stg0 = (wid >> 2) * TS2 + (2 * (wid & 3)) * 65 + lane;
    const int stg1 = stg0 + 65;
    // tile read base for this lane: j = 4h at column cg
    const int trb = (4 * h) * 65 + cg;

    float4 sB, sC;
    if (XF) sB = Bs[Bb + tid];                 // tile 0 of B, issued early

    // ---- Phase 0: coalesced load of delta/u -> step-major packed LDS ----
#pragma unroll
    for (int p = 0; p < 2; ++p) {
        const int l0 = 4 * t128 + 512 * p;
        const size_t gb = (size_t)row * L + l0;
        const float4 d4 = *reinterpret_cast<const float4*>(&delta_g[gb]);
        const float4 u4 = *reinterpret_cast<const float4*>(&u_g[gb]);
        const float bias = bias_g[d];
        const int sp = sp_g[0];
#pragma unroll
        for (int k = 0; k < 4; ++k) {
            const int li = l0 + k;
            const float t = (&d4.x)[k] + bias;
            // softplus: max(t,0) + ln(1 + 2^(-|t|*log2e))
            const float e = EXP2(-fabsf(t) * LOG2E);
            const float p_ = sp ? (fmaxf(t, 0.f) +
                                   __builtin_amdgcn_logf(1.f + e) * RLOG2E)
                                : t;
            const int a = (li & (CL - 1)) * ISTR2 + (li >> 4);  // [step][chunk]
            du_s[lb + a] = make_float2(p_, (&u4.x)[k]);
        }
    }
    float A2[8];
#pragma unroll
    for (int g = 0; g < 2; ++g) {
        const float4 a4 = *reinterpret_cast<const float4*>(&A_g[d * N + h * 8 + g * 4]);
        A2[g * 4 + 0] = a4.x * LOG2E; A2[g * 4 + 1] = a4.y * LOG2E;
        A2[g * 4 + 2] = a4.z * LOG2E; A2[g * 4 + 3] = a4.w * LOG2E;
    }
    if (XF) {                                  // stage tile 0 (B) for pass 1
        tb2[0][stg0] = make_float2(sB.x, sB.y);
        tb2[0][stg1] = make_float2(sB.z, sB.w);
    }
    __syncthreads();

    // ---- Pass 1: chunk-local zero-init scan; B via b64 LDS tiles (dbuf) ----
    float x[8], y[8];
#pragma unroll
    for (int n = 0; n < 8; ++n) { x[n] = 0.f; y[n] = 0.f; }
    float ssum = 0.f;

    if (XF) {
#pragma unroll
        for (int t = 0; t < NT; ++t) {
            if (t + 1 < NT) sB = Bs[Bb + (t + 1) * 512 + tid];  // prefetch
#pragma unroll
            for (int il = 0; il < TI; ++il) {
                const int i = t * TI + il;
                const float2 du = du_s[lb + i * ISTR2 + cg];
                const float dtp = du.x;
                const float dtu = du.x * du.y;
                ssum += dtp;
                const int rb = il * TS2 + trb;
                const float2 q0 = tb2[t & 1][rb];
                const float2 q1 = tb2[t & 1][rb + 65];
                const float2 q2 = tb2[t & 1][rb + 130];
                const float2 q3 = tb2[t & 1][rb + 195];
                const float bv[8] = {q0.x, q0.y, q1.x, q1.y,
                                     q2.x, q2.y, q3.x, q3.y};
#pragma unroll
                for (int n = 0; n < 8; ++n) {
                    const float a = EXP2(dtp * A2[n]);
                    x[n] = fmaf(a, x[n], dtu * bv[n]);
                }
            }
            if (t + 1 < NT) {
                tb2[(t + 1) & 1][stg0] = make_float2(sB.x, sB.y);
                tb2[(t + 1) & 1][stg1] = make_float2(sB.z, sB.w);
            }
            __syncthreads();                   // end tile epoch
        }
    } else {
#pragma unroll
        for (int i = 0; i < CL; ++i) {
            const float2 du = du_s[lb + i * ISTR2 + cg];
            const float dtp = du.x;
            const float dtu = du.x * du.y;
            ssum += dtp;
            const int l = cg * CL + i;
            const int k0 = 2 * h;
            float4 B0, B1;
#pragma unroll
            for (int q = 0; q < 4; ++q) {
                (&B0.x)[q] = B_g[(size_t)(b * N + 4 * k0 + q) * L + l];
                (&B1.x)[q] = B_g[(size_t)(b * N + 4 * k0 + 4 + q) * L + l];
            }
            const float bv[8] = {B0.x, B0.y, B0.z, B0.w, B1.x, B1.y, B1.z, B1.w};
#pragma unroll
            for (int n = 0; n < 8; ++n) {
                const float a = EXP2(dtp * A2[n]);
                x[n] = fmaf(a, x[n], dtu * bv[n]);
            }
        }
    }

    // issue pass-2 tile 0 loads early (latency hides under combine)
    if (XF) { sB = Bs[Bb + tid]; sC = Cs[Bb + tid]; }

    // ---- Combine level 1: 32-lane segmented inclusive scan of (P, x) ----
    float P[8];
#pragma unroll
    for (int n = 0; n < 8; ++n) P[n] = EXP2(A2[n] * ssum);
#pragma unroll
    for (int s = 1; s < 32; s <<= 1) {
        const bool ok = (c >= s);
#pragma unroll
        for (int n = 0; n < 8; ++n) {
            const float xp = __shfl_up(x[n], s, 32);
            const float Pp = __shfl_up(P[n], s, 32);
            if (ok) {
                x[n] = fmaf(P[n], xp, x[n]);
                P[n] = P[n] * Pp;
            }
        }
    }

    // ---- Combine level 2 publish + stage pass-2 tile 0; ONE barrier ----
    if (W == 0 && c == 31) {
#pragma unroll
        for (int n = 0; n < 8; ++n) xw_s[r][h * 8 + n] = x[n];
    }
    if (XF) {
        tb2[0][stg0] = make_float2(sB.x, sB.y);
        tb2[0][stg1] = make_float2(sB.z, sB.w);
        tb2[1][stg0] = make_float2(sC.x, sC.y);
        tb2[1][stg1] = make_float2(sC.z, sC.w);
    }
    __syncthreads();

    // exclusive shift within segment + wave1 prepends wave0's total
    float xt[8];
#pragma unroll
    for (int n = 0; n < 8; ++n) xt[n] = xw_s[r][h * 8 + n];
#pragma unroll
    for (int n = 0; n < 8; ++n) {
        const float xi = __shfl_up(x[n], 1, 32);
        const float Pi = __shfl_up(P[n], 1, 32);
        const float xe = (c == 0) ? 0.f : xi;
        const float Pe = (c == 0) ? 1.f : Pi;
        x[n] = W ? fmaf(Pe, xt[n], xe) : xe;
    }

    // ---- Pass 2: rescan with init states; y -> registers ----
    const float Dd = D_g[d];
    if (XF) {
#pragma unroll
        for (int t = 0; t < NT; ++t) {
            if (t + 1 < NT) {
                sB = Bs[Bb + (t + 1) * 512 + tid];   // prefetch next tile
                sC = Cs[Bb + (t + 1) * 512 + tid];
            }
#pragma unroll
            for (int il = 0; il < TI; ++il) {
                const int i = t * TI + il;
                const float2 du = du_s[lb + i * ISTR2 + cg];
                const float dtp = du.x;
                const float uu = du.y;
                const float dtu = dtp * uu;
                const int rb = il * TS2 + trb;
                const float2 b0 = tb2[0][rb];
                const float2 b1 = tb2[0][rb + 65];
                const float2 b2 = tb2[0][rb + 130];
                const float2 b3 = tb2[0][rb + 195];
                const float2 c0 = tb2[1][rb];
                const float2 c1 = tb2[1][rb + 65];
                const float2 c2 = tb2[1][rb + 130];
                const float2 c3 = tb2[1][rb + 195];
                const float bv[8] = {b0.x, b0.y, b1.x, b1.y,
                                     b2.x, b2.y, b3.x, b3.y};
                const float cv[8] = {c0.x, c0.y, c1.x, c1.y,
                                     c2.x, c2.y, c3.x, c3.y};
                float acc = 0.f;
#pragma unroll
                for (int n = 0; n < 8; ++n) {
                    const float a = EXP2(dtp * A2[n]);
                    x[n] = fmaf(a, x[n], dtu * bv[n]);
                    acc = fmaf(x[n], cv[n], acc);
                }
                acc += __shfl_xor(acc, 32, 64);    // both halves get full sum
                const float yv = fmaf(uu, Dd, acc);
                y[i & 7] = ((i >> 3) == h) ? yv : y[i & 7];   // static idx
            }
            __syncthreads();                       // all waves done with tile t
            if (t + 1 < NT) {
                tb2[0][stg0] = make_float2(sB.x, sB.y);
                tb2[0][stg1] = make_float2(sB.z, sB.w);
                tb2[1][stg0] = make_float2(sC.x, sC.y);
                tb2[1][stg1] = make_float2(sC.z, sC.w);
                __syncthreads();                   // tile t+1 visible
            }
        }
    } else {
#pragma unroll
        for (int i = 0; i < CL; ++i) {
            const float2 du = du_s[lb + i * ISTR2 + cg];
            const float dtp = du.x;
            const float uu = du.y;
            const float dtu = dtp * uu;
            const int l = cg * CL + i;
            const int k0 = 2 * h;
            float4 B0, B1, C0, C1;
#pragma unroll
            for (int q = 0; q < 4; ++q) {
                (&B0.x)[q] = B_g[(size_t)(b * N + 4 * k0 + q) * L + l];
                (&B1.x)[q] = B_g[(size_t)(b * N + 4 * k0 + 4 + q) * L + l];
                (&C0.x)[q] = C_g[(size_t)(b * N + 4 * k0 + q) * L + l];
                (&C1.x)[q] = C_g[(size_t)(b * N + 4 * k0 + 4 + q) * L + l];
            }
            const float bv[8] = {B0.x, B0.y, B0.z, B0.w, B1.x, B1.y, B1.z, B1.w};
            const float cv[8] = {C0.x, C0.y, C0.z, C0.w, C1.x, C1.y, C1.z, C1.w};
            float acc = 0.f;
#pragma unroll
            for (int n = 0; n < 8; ++n) {
                const float a = EXP2(dtp * A2[n]);
                x[n] = fmaf(a, x[n], dtu * bv[n]);
                acc = fmaf(x[n], cv[n], acc);
            }
            acc += __shfl_xor(acc, 32, 64);
            const float yv = fmaf(uu, Dd, acc);
            y[i & 7] = ((i >> 3) == h) ? yv : y[i & 7];
        }
    }

    // ---- Epilogue: per-lane z read (32B), silu gate, y store from regs ----
    // lane (h,c) owns elements [cg*16 + h*8, +8); wave coverage dense.
    {
        const size_t gz = (size_t)row * L + cg * CL + h * 8;
        const float4 z0 = *reinterpret_cast<const float4*>(&z_g[gz]);
        const float4 z1 = *reinterpret_cast<const float4*>(&z_g[gz + 4]);
        float out[8];
#pragma unroll
        for (int j = 0; j < 8; ++j) {
            const float zv = (j < 4) ? (&z0.x)[j] : (&z1.x)[j - 4];
            const float e = EXP2(-zv * LOG2E);
            const float sig = __builtin_amdgcn_rcpf(1.f + e);
            out[j] = y[j] * (zv * sig);
        }
        *reinterpret_cast<float4*>(&y_g[gz]) =
            make_float4(out[0], out[1], out[2], out[3]);
        *reinterpret_cast<float4*>(&y_g[gz + 4]) =
            make_float4(out[4], out[5], out[6], out[7]);
    }
}

extern "C" void kernel_launch(void* const* d_in, const int* in_sizes, int n_in,
                              void* d_out, int out_size, void* d_ws, size_t ws_size,
                              hipStream_t stream) {
    const float* u     = (const float*)d_in[0];
    const float* delta = (const float*)d_in[1];
    const float* A     = (const float*)d_in[2];
    const float* B     = (const float*)d_in[3];
    const float* C     = (const float*)d_in[4];
    const float* D     = (const float*)d_in[5];
    const float* z     = (const float*)d_in[6];
    const float* bias  = (const float*)d_in[7];
    const int*   sp    = (const int*)d_in[8];
    float* y = (float*)d_out;

    const size_t bc_bytes = (size_t)Bsz * 4096 * sizeof(float4);  // 128 KB each
    const bool xf = ws_size >= 2 * bc_bytes;
    float4* Bs = (float4*)d_ws;
    float4* Cs = (float4*)((char*)d_ws + bc_bytes);

    if (xf) {
        transform_bc_kernel<<<dim3(16, Bsz, 2), 256, 0, stream>>>(B, C, Bs, Cs);
        mamba_scan18_kernel<true><<<dim3((Bsz * Dm) / RPB), TPB, 0, stream>>>(
            u, delta, A, B, C, Bs, Cs, D, z, bias, sp, y);
    } else {
        mamba_scan18_kernel<false><<<dim3((Bsz * Dm) / RPB), TPB, 0, stream>>>(
            u, delta, A, B, C, Bs, Cs, D, z, bias, sp, y);
    }
}